// Round 2
// baseline (739.899 us; speedup 1.0000x reference)
//
#include <hip/hip_runtime.h>
#include <stdint.h>

#define BB 32
#define LL 1024
#define CC 512
#define NN (BB * LL)      // 32768 positions
#define NLEVS 4
#define OUTD 11

typedef __attribute__((ext_vector_type(8))) short bf16x8;
typedef __attribute__((ext_vector_type(4))) float f32x4;

static __device__ __forceinline__ unsigned short f2bf(float f) {
    union { float f; uint32_t u; } v; v.f = f;
    uint32_t u = v.u;
    uint32_t r = (u + 0x7fffu + ((u >> 16) & 1u)) >> 16;  // RNE
    return (unsigned short)r;
}

// h0[n][c] = emb[x[n]][c]  (fp32, [N][C] row-major)
__global__ __launch_bounds__(256) void embed_kernel(
    const int* __restrict__ x, const float* __restrict__ emb, float* __restrict__ h)
{
    int t = blockIdx.x * 256 + threadIdx.x;   // one float4 each
    int n = t >> 7;                            // 128 float4 per row
    int c4 = t & 127;
    int idx = x[n];
    ((float4*)(h + (size_t)n * CC))[c4] = ((const float4*)(emb + (size_t)idx * CC))[c4];
}

// Wp[lvl][conv][co][kidx]: kidx<512 -> w[lvl][co][kidx][1] (current tap),
//                          kidx>=512 -> w[lvl][co][kidx-512][0] (past tap)
__global__ __launch_bounds__(256) void pack_w_kernel(
    const float* __restrict__ w1, const float* __restrict__ w2, unsigned short* __restrict__ Wp)
{
    int e = blockIdx.x * 256 + threadIdx.x;    // 4*2*512*1024 elements
    int kidx = e & 1023;
    int co = (e >> 10) & 511;
    int conv = (e >> 19) & 1;
    int lvl = e >> 20;
    int tap = (kidx < 512) ? 1 : 0;
    int ci = kidx & 511;
    const float* w = conv ? w2 : w1;
    float val = w[(((size_t)(lvl * 512 + co) * 512) + ci) * 2 + tap];
    Wp[e] = f2bf(val);
}

// out[n][co] = act( Hin-window . Wp[co][:] + bias[co] ),  [N][C] fp32 in/out
// HAS_RES: out = relu(relu(acc+b) + res)  else  out = relu(acc+b)
template <bool HAS_RES>
__global__ __launch_bounds__(256, 2) void conv_gemm(
    const float* __restrict__ Hin, const unsigned short* __restrict__ Wp,
    const float* __restrict__ bias, const float* __restrict__ res,
    float* __restrict__ Out, int d)
{
    __shared__ unsigned short lA[128][40];  // n-rows x k, pad 32->40 (80B stride)
    __shared__ unsigned short lB[128][40];  // co-rows x k

    const int tid = threadIdx.x;
    const int n0 = blockIdx.x * 128;
    const int co0 = blockIdx.y * 128;
    const int wave = tid >> 6, lane = tid & 63;
    const int wm = (wave >> 1) * 64, wn = (wave & 1) * 64;
    const int lm = lane & 15, quad = lane >> 4;

    f32x4 acc[4][4];
#pragma unroll
    for (int i = 0; i < 4; ++i)
#pragma unroll
        for (int j = 0; j < 4; ++j) acc[i][j] = (f32x4){0.f, 0.f, 0.f, 0.f};

    for (int kk = 0; kk < 32; ++kk) {
        const int shift = (kk < 16) ? 0 : d;       // kk 0..15: tap1; 16..31: tap0
        const int ci0 = (kk & 15) * 32;
        const int kidx0 = kk * 32;

        // stage A: 128 rows x 32 fp32 -> bf16 LDS (1024 float4 chunks, 4/thread)
#pragma unroll
        for (int i = 0; i < 4; ++i) {
            int c = tid + i * 256;
            int r = c >> 3, col = (c & 7) * 4;
            int n = n0 + r;
            int l = n & (LL - 1);
            float4 v = {0.f, 0.f, 0.f, 0.f};
            if (l >= shift)
                v = *(const float4*)(Hin + (size_t)(n - shift) * CC + ci0 + col);
            ushort4 w4;
            w4.x = f2bf(v.x); w4.y = f2bf(v.y); w4.z = f2bf(v.z); w4.w = f2bf(v.w);
            *(ushort4*)&lA[r][col] = w4;
        }
        // stage B: 128 rows x 32 bf16 (512 x 16B chunks, 2/thread)
#pragma unroll
        for (int i = 0; i < 2; ++i) {
            int c = tid + i * 256;
            int r = c >> 2, col = (c & 3) * 8;
            uint4 v = *(const uint4*)(Wp + (size_t)(co0 + r) * 1024 + kidx0 + col);
            *(uint4*)&lB[r][col] = v;
        }
        __syncthreads();

        bf16x8 af[4], bfr[4];
#pragma unroll
        for (int mt = 0; mt < 4; ++mt)
            af[mt] = *(const bf16x8*)&lA[wm + mt * 16 + lm][quad * 8];
#pragma unroll
        for (int nt = 0; nt < 4; ++nt)
            bfr[nt] = *(const bf16x8*)&lB[wn + nt * 16 + lm][quad * 8];
#pragma unroll
        for (int mt = 0; mt < 4; ++mt)
#pragma unroll
            for (int nt = 0; nt < 4; ++nt)
                acc[mt][nt] = __builtin_amdgcn_mfma_f32_16x16x32_bf16(
                    af[mt], bfr[nt], acc[mt][nt], 0, 0, 0);
        __syncthreads();
    }

    // epilogue: C/D layout col=lane&15 (co), row=quad*4+reg (n)
#pragma unroll
    for (int mt = 0; mt < 4; ++mt) {
#pragma unroll
        for (int nt = 0; nt < 4; ++nt) {
            int co = co0 + wn + nt * 16 + lm;
            float bv = bias[co];
#pragma unroll
            for (int r = 0; r < 4; ++r) {
                int n = n0 + wm + mt * 16 + quad * 4 + r;
                float v = acc[mt][nt][r] + bv;
                v = fmaxf(v, 0.f);
                if (HAS_RES) {
                    v += res[(size_t)n * CC + co];
                    v = fmaxf(v, 0.f);
                }
                Out[(size_t)n * CC + co] = v;
            }
        }
    }
}

// y[n][o] = mask[n] * (sum_c h[n][c]*dw[o][c] + db[o]);  one wave per n
// mask is int32 (harness stages jnp.bool_ as int32: "integer -> const int*")
__global__ __launch_bounds__(256) void decode_kernel(
    const float* __restrict__ H, const float* __restrict__ dw,
    const float* __restrict__ db, const int* __restrict__ mask,
    float* __restrict__ out)
{
    __shared__ float sw[OUTD * CC];
    for (int i = threadIdx.x; i < OUTD * CC; i += 256) sw[i] = dw[i];
    __syncthreads();

    int wave = threadIdx.x >> 6, lane = threadIdx.x & 63;
    int n = blockIdx.x * 4 + wave;

    float hv[8];
#pragma unroll
    for (int j = 0; j < 8; ++j) hv[j] = H[(size_t)n * CC + lane + j * 64];

    float accv[OUTD];
#pragma unroll
    for (int o = 0; o < OUTD; ++o) {
        float s = 0.f;
#pragma unroll
        for (int j = 0; j < 8; ++j) s += hv[j] * sw[o * CC + lane + j * 64];
        accv[o] = s;
    }
    float myv = 0.f;
#pragma unroll
    for (int o = 0; o < OUTD; ++o) {
        float s = accv[o];
#pragma unroll
        for (int m = 32; m; m >>= 1) s += __shfl_xor(s, m, 64);
        if (lane == o) myv = s;
    }
    if (lane < OUTD) {
        float mk = (mask[n] != 0) ? 1.f : 0.f;
        out[(size_t)n * OUTD + lane] = (myv + db[lane]) * mk;
    }
}

extern "C" void kernel_launch(void* const* d_in, const int* in_sizes, int n_in,
                              void* d_out, int out_size, void* d_ws, size_t ws_size,
                              hipStream_t stream)
{
    const int* x = (const int*)d_in[0];
    const int* mask = (const int*)d_in[1];   // jnp bool_ staged as int32
    const float* emb = (const float*)d_in[2];
    const float* w1 = (const float*)d_in[3];
    const float* b1 = (const float*)d_in[4];
    const float* w2 = (const float*)d_in[5];
    const float* b2 = (const float*)d_in[6];
    const float* dw = (const float*)d_in[7];
    const float* db = (const float*)d_in[8];
    float* out = (float*)d_out;

    char* ws = (char*)d_ws;
    const size_t HBYTES = (size_t)NN * CC * 4;           // 64 MB
    float* P0 = (float*)ws;                               // h (fp32 carry)
    float* P1 = (float*)(ws + HBYTES);                    // mid buffer
    unsigned short* Wp = (unsigned short*)(ws + 2 * HBYTES);  // packed bf16 weights, 8 MB

    embed_kernel<<<(NN * (CC / 4)) / 256, 256, 0, stream>>>(x, emb, P0);
    pack_w_kernel<<<(NLEVS * 2 * CC * 1024) / 256, 256, 0, stream>>>(w1, w2, Wp);

    dim3 g(NN / 128, CC / 128);
    for (int i = 0; i < NLEVS; ++i) {
        int d = 1 << i;
        const unsigned short* Wp1 = Wp + (size_t)(i * 2 + 0) * CC * 1024;
        const unsigned short* Wp2 = Wp + (size_t)(i * 2 + 1) * CC * 1024;
        conv_gemm<false><<<g, 256, 0, stream>>>(P0, Wp1, b1 + i * CC, nullptr, P1, d);
        conv_gemm<true><<<g, 256, 0, stream>>>(P1, Wp2, b2 + i * CC, P0, P0, d);
    }
    decode_kernel<<<NN / 4, 256, 0, stream>>>(P0, dw, db, mask, out);
}

// Round 3
// 604.728 us; speedup vs baseline: 1.2235x; 1.2235x over previous
//
#include <hip/hip_runtime.h>
#include <stdint.h>

#define BB 32
#define LL 1024
#define CC 512
#define NN (BB * LL)      // 32768 positions
#define NLEVS 4
#define OUTD 11
#define LPAD 8            // zero pad rows per sequence (>= max dilation)
#define LROWS (LL + LPAD) // 1032 padded rows per sequence

typedef __attribute__((ext_vector_type(8))) short bf16x8;
typedef __attribute__((ext_vector_type(4))) float f32x4;

static __device__ __forceinline__ unsigned short f2bf(float f) {
    union { float f; uint32_t u; } v; v.f = f;
    uint32_t u = v.u;
    uint32_t r = (u + 0x7fffu + ((u >> 16) & 1u)) >> 16;  // RNE
    return (unsigned short)r;
}

// async 16B global -> LDS (wave-uniform LDS base + lane*16)
static __device__ __forceinline__ void llds16(const unsigned short* g, unsigned short* l) {
    __builtin_amdgcn_global_load_lds(
        (const __attribute__((address_space(1))) unsigned int*)g,
        (__attribute__((address_space(3))) unsigned int*)l, 16, 0, 0);
}

// zero the LPAD pad rows of both bf16 activation buffers (ws is re-poisoned every call)
__global__ __launch_bounds__(256) void zero_pad_kernel(
    unsigned short* __restrict__ Hb0, unsigned short* __restrict__ Hb1)
{
    int t = blockIdx.x * 256 + threadIdx.x;        // 32768 uint4 stores
    unsigned short* base = (t >> 14) ? Hb1 : Hb0;
    int rem = t & 16383;
    int p = rem >> 9;                               // sequence 0..31
    int q = rem & 511;                              // 512 uint4 per pad region
    size_t off = (size_t)p * (LROWS * CC) + (size_t)q * 8;  // halves
    *(uint4*)(base + off) = (uint4){0u, 0u, 0u, 0u};
}

// h0: fp32 [N][C] (residual/decode carry) + bf16 padded copy (GEMM A operand)
__global__ __launch_bounds__(256) void embed_kernel(
    const int* __restrict__ x, const float* __restrict__ emb,
    float* __restrict__ h, unsigned short* __restrict__ Hb0)
{
    int t = blockIdx.x * 256 + threadIdx.x;   // one float4 each
    int n = t >> 7;                            // 128 float4 per row
    int c4 = t & 127;
    int idx = x[n];
    float4 v = ((const float4*)(emb + (size_t)idx * CC))[c4];
    ((float4*)(h + (size_t)n * CC))[c4] = v;
    int prow = (n >> 10) * LROWS + LPAD + (n & (LL - 1));
    ushort4 w4;
    w4.x = f2bf(v.x); w4.y = f2bf(v.y); w4.z = f2bf(v.z); w4.w = f2bf(v.w);
    *(ushort4*)(Hb0 + (size_t)prow * CC + c4 * 4) = w4;
}

// Wp[lvl][conv][co][kidx]: kidx<512 -> w[lvl][co][kidx][1] (current tap),
//                          kidx>=512 -> w[lvl][co][kidx-512][0] (past tap)
__global__ __launch_bounds__(256) void pack_w_kernel(
    const float* __restrict__ w1, const float* __restrict__ w2, unsigned short* __restrict__ Wp)
{
    int e = blockIdx.x * 256 + threadIdx.x;    // 4*2*512*1024 elements
    int kidx = e & 1023;
    int co = (e >> 10) & 511;
    int conv = (e >> 19) & 1;
    int lvl = e >> 20;
    int tap = (kidx < 512) ? 1 : 0;
    int ci = kidx & 511;
    const float* w = conv ? w2 : w1;
    float val = w[(((size_t)(lvl * 512 + co) * 512) + ci) * 2 + tap];
    Wp[e] = f2bf(val);
}

// GEMM: out[n][co] = act( A-window . Wp[co][:] + bias[co] )
// A from padded bf16 buffer (shift handled by row offset into pad rows).
// HAS_RES: v = relu(relu(acc+b) + resF[n][co]); writes fp32 OutF AND bf16 OutB.
// else:    v = relu(acc+b); writes bf16 OutB only.
// 128x128 tile, BK=64, XOR-swizzled LDS (chunk ^ row&7) -> 2-way-max bank access.
template <bool HAS_RES>
__global__ __launch_bounds__(256) void conv_gemm(
    const unsigned short* __restrict__ Ain, const unsigned short* __restrict__ Wp,
    const float* __restrict__ bias, const float* __restrict__ resF,
    float* __restrict__ OutF, unsigned short* __restrict__ OutB, int d)
{
    __shared__ unsigned short sA[128 * 64];
    __shared__ unsigned short sB[128 * 64];

    const int tid = threadIdx.x;
    const int wave = tid >> 6, lane = tid & 63;
    const int co0 = blockIdx.x * 128;          // co-minor: 4 co-blocks share A rows
    const int n0 = blockIdx.y * 128;
    const int rbase = (n0 >> 10) * LROWS + LPAD + (n0 & (LL - 1));  // padded row of n0
    const int r8 = lane >> 3;                  // 0..7: row within 8-row segment
    const int cswz = (lane & 7) ^ r8;          // swizzled 16B chunk for staging
    const int wm = (wave >> 1) * 64, wn = (wave & 1) * 64;
    const int lm = lane & 15, quad = lane >> 4;
    const int lm7 = lm & 7;

    f32x4 acc[4][4];
#pragma unroll
    for (int i = 0; i < 4; ++i)
#pragma unroll
        for (int j = 0; j < 4; ++j) acc[i][j] = (f32x4){0.f, 0.f, 0.f, 0.f};

    for (int it = 0; it < 16; ++it) {
        const int shift = (it < 8) ? 0 : d;        // K order: [tap1 512 | tap0 512]
        const int ci0 = (it & 7) * 64;
        const int kidx0 = it * 64;

        // stage A: wave w covers rows 32w..32w+31 (4 x 1KB wave-segments)
        const unsigned short* gA =
            Ain + (size_t)(rbase - shift + 32 * wave + r8) * CC + ci0 + cswz * 8;
        unsigned short* lA = sA + (32 * wave) * 64;
#pragma unroll
        for (int s = 0; s < 4; ++s)
            llds16(gA + (size_t)s * 8 * CC, lA + s * 8 * 64);

        // stage B: same pattern over Wp rows (co)
        const unsigned short* gB =
            Wp + (size_t)(co0 + 32 * wave + r8) * 1024 + kidx0 + cswz * 8;
        unsigned short* lB = sB + (32 * wave) * 64;
#pragma unroll
        for (int s = 0; s < 4; ++s)
            llds16(gB + (size_t)s * 8 * 1024, lB + s * 8 * 64);

        __syncthreads();

#pragma unroll
        for (int kc = 0; kc < 2; ++kc) {
            bf16x8 af[4], bfr[4];
#pragma unroll
            for (int mt = 0; mt < 4; ++mt)
                af[mt] = *(const bf16x8*)&sA[(wm + mt * 16 + lm) * 64 +
                                             (((kc * 4 + quad) ^ lm7) * 8)];
#pragma unroll
            for (int nt = 0; nt < 4; ++nt)
                bfr[nt] = *(const bf16x8*)&sB[(wn + nt * 16 + lm) * 64 +
                                              (((kc * 4 + quad) ^ lm7) * 8)];
#pragma unroll
            for (int mt = 0; mt < 4; ++mt)
#pragma unroll
                for (int nt = 0; nt < 4; ++nt)
                    acc[mt][nt] = __builtin_amdgcn_mfma_f32_16x16x32_bf16(
                        af[mt], bfr[nt], acc[mt][nt], 0, 0, 0);
        }
        __syncthreads();
    }

    // epilogue: C/D layout col(co)=lane&15, row(n)=quad*4+reg
#pragma unroll
    for (int mt = 0; mt < 4; ++mt) {
#pragma unroll
        for (int nt = 0; nt < 4; ++nt) {
            int co = co0 + wn + nt * 16 + lm;
            float bv = bias[co];
#pragma unroll
            for (int r = 0; r < 4; ++r) {
                int n = n0 + wm + mt * 16 + quad * 4 + r;
                float v = acc[mt][nt][r] + bv;
                v = fmaxf(v, 0.f);
                if (HAS_RES) {
                    v += resF[(size_t)n * CC + co];
                    v = fmaxf(v, 0.f);
                    OutF[(size_t)n * CC + co] = v;
                }
                int prow = rbase + (n - n0);
                OutB[(size_t)prow * CC + co] = f2bf(v);
            }
        }
    }
}

// y[n][o] = mask[n] * (sum_c h[n][c]*dw[o][c] + db[o]);  one wave per n (fp32 h)
__global__ __launch_bounds__(256) void decode_kernel(
    const float* __restrict__ H, const float* __restrict__ dw,
    const float* __restrict__ db, const int* __restrict__ mask,
    float* __restrict__ out)
{
    __shared__ float sw[OUTD * CC];
    for (int i = threadIdx.x; i < OUTD * CC; i += 256) sw[i] = dw[i];
    __syncthreads();

    int wave = threadIdx.x >> 6, lane = threadIdx.x & 63;
    int n = blockIdx.x * 4 + wave;

    float hv[8];
#pragma unroll
    for (int j = 0; j < 8; ++j) hv[j] = H[(size_t)n * CC + lane + j * 64];

    float accv[OUTD];
#pragma unroll
    for (int o = 0; o < OUTD; ++o) {
        float s = 0.f;
#pragma unroll
        for (int j = 0; j < 8; ++j) s += hv[j] * sw[o * CC + lane + j * 64];
        accv[o] = s;
    }
    float myv = 0.f;
#pragma unroll
    for (int o = 0; o < OUTD; ++o) {
        float s = accv[o];
#pragma unroll
        for (int m = 32; m; m >>= 1) s += __shfl_xor(s, m, 64);
        if (lane == o) myv = s;
    }
    if (lane < OUTD) {
        float mk = (mask[n] != 0) ? 1.f : 0.f;
        out[(size_t)n * OUTD + lane] = (myv + db[lane]) * mk;
    }
}

extern "C" void kernel_launch(void* const* d_in, const int* in_sizes, int n_in,
                              void* d_out, int out_size, void* d_ws, size_t ws_size,
                              hipStream_t stream)
{
    const int* x = (const int*)d_in[0];
    const int* mask = (const int*)d_in[1];   // jnp bool_ staged as int32
    const float* emb = (const float*)d_in[2];
    const float* w1 = (const float*)d_in[3];
    const float* b1 = (const float*)d_in[4];
    const float* w2 = (const float*)d_in[5];
    const float* b2 = (const float*)d_in[6];
    const float* dw = (const float*)d_in[7];
    const float* db = (const float*)d_in[8];
    float* out = (float*)d_out;

    char* ws = (char*)d_ws;
    const size_t F32B = (size_t)NN * CC * 4;              // 64 MB
    const size_t HBB = (size_t)BB * LROWS * CC * 2;       // 33.8 MB (padded bf16)
    float* P0 = (float*)ws;                                // fp32 carry (residual + decode)
    unsigned short* Hb0 = (unsigned short*)(ws + F32B);
    unsigned short* Hb1 = (unsigned short*)(ws + F32B + HBB);
    unsigned short* Wp = (unsigned short*)(ws + F32B + 2 * HBB);  // packed bf16 weights, 8 MB

    zero_pad_kernel<<<128, 256, 0, stream>>>(Hb0, Hb1);
    embed_kernel<<<(NN * (CC / 4)) / 256, 256, 0, stream>>>(x, emb, P0, Hb0);
    pack_w_kernel<<<(NLEVS * 2 * CC * 1024) / 256, 256, 0, stream>>>(w1, w2, Wp);

    dim3 g(CC / 128, NN / 128);   // x = co-block (4), y = n-block (256)
    for (int i = 0; i < NLEVS; ++i) {
        int d = 1 << i;
        const unsigned short* Wp1 = Wp + (size_t)(i * 2 + 0) * CC * 1024;
        const unsigned short* Wp2 = Wp + (size_t)(i * 2 + 1) * CC * 1024;
        // conv1: A=Hb0, out bf16 -> Hb1
        conv_gemm<false><<<g, 256, 0, stream>>>(Hb0, Wp1, b1 + i * CC,
                                                nullptr, nullptr, Hb1, d);
        // conv2: A=Hb1, res fp32 P0, out fp32 P0 + bf16 Hb0
        conv_gemm<true><<<g, 256, 0, stream>>>(Hb1, Wp2, b2 + i * CC,
                                               P0, P0, Hb0, d);
    }
    decode_kernel<<<NN / 4, 256, 0, stream>>>(P0, dw, db, mask, out);
}

// Round 4
// 479.216 us; speedup vs baseline: 1.5440x; 1.2619x over previous
//
#include <hip/hip_runtime.h>
#include <stdint.h>

#define BB 32
#define LL 1024
#define CC 512
#define NN (BB * LL)      // 32768 positions
#define NLEVS 4
#define OUTD 11
#define LPAD 8            // zero pad rows per sequence (>= max dilation)
#define LROWS (LL + LPAD) // 1032 padded rows per sequence

typedef __attribute__((ext_vector_type(8))) short bf16x8;
typedef __attribute__((ext_vector_type(4))) float f32x4;

static __device__ __forceinline__ unsigned short f2bf(float f) {
    union { float f; uint32_t u; } v; v.f = f;
    uint32_t u = v.u;
    uint32_t r = (u + 0x7fffu + ((u >> 16) & 1u)) >> 16;  // RNE
    return (unsigned short)r;
}
static __device__ __forceinline__ float bf2f(unsigned short h) {
    union { uint32_t u; float f; } v; v.u = ((uint32_t)h) << 16;
    return v.f;
}

// async 16B global -> LDS (wave-uniform LDS base + lane*16)
static __device__ __forceinline__ void llds16(const unsigned short* g, unsigned short* l) {
    __builtin_amdgcn_global_load_lds(
        (const __attribute__((address_space(1))) unsigned int*)g,
        (__attribute__((address_space(3))) unsigned int*)l, 16, 0, 0);
}

// zero the LPAD pad rows of both bf16 activation buffers
__global__ __launch_bounds__(256) void zero_pad_kernel(
    unsigned short* __restrict__ Hb0, unsigned short* __restrict__ Hb1)
{
    int t = blockIdx.x * 256 + threadIdx.x;        // 32768 uint4 stores
    unsigned short* base = (t >> 14) ? Hb1 : Hb0;
    int rem = t & 16383;
    int p = rem >> 9;                               // sequence 0..31
    int q = rem & 511;                              // 512 uint4 per pad region
    size_t off = (size_t)p * (LROWS * CC) + (size_t)q * 8;
    *(uint4*)(base + off) = (uint4){0u, 0u, 0u, 0u};
}

// h0 bf16 padded: Hb0[prow][c] = bf16(emb[x[n]][c])
__global__ __launch_bounds__(256) void embed_kernel(
    const int* __restrict__ x, const float* __restrict__ emb,
    unsigned short* __restrict__ Hb0)
{
    int t = blockIdx.x * 256 + threadIdx.x;   // 8 halves each (64 chunks/row)
    int n = t >> 6;
    int c8 = (t & 63) * 8;
    int idx = x[n];
    const float* src = emb + (size_t)idx * CC + c8;
    float4 v0 = *(const float4*)src;
    float4 v1 = *(const float4*)(src + 4);
    ushort4 a, b;
    a.x = f2bf(v0.x); a.y = f2bf(v0.y); a.z = f2bf(v0.z); a.w = f2bf(v0.w);
    b.x = f2bf(v1.x); b.y = f2bf(v1.y); b.z = f2bf(v1.z); b.w = f2bf(v1.w);
    int prow = (n >> 10) * LROWS + LPAD + (n & (LL - 1));
    unsigned short* dst = Hb0 + (size_t)prow * CC + c8;
    *(ushort4*)dst = a;
    *(ushort4*)(dst + 4) = b;
}

// WpT[cv][j][co][h]: k-chunk-major packed weights for direct B-fragment loads.
// kidx = j*8+h; kidx<512 -> tap "current" (k=1, ci=kidx); kidx>=512 -> k=0, ci=kidx-512.
__global__ __launch_bounds__(256) void pack_w_kernel(
    const float* __restrict__ w1, const float* __restrict__ w2, unsigned short* __restrict__ WpT)
{
    int e = blockIdx.x * 256 + threadIdx.x;    // 8 * 524288 elements
    int cv = e >> 19;                           // conv 0..7 (lvl*2+conv)
    int r = e & 524287;
    int j = r >> 12;                            // 0..127
    int co = (r >> 3) & 511;
    int h = r & 7;
    int kidx = j * 8 + h;
    int k = (kidx < 512) ? 1 : 0;
    int ci = kidx & 511;
    int lvl = cv >> 1;
    const float* w = (cv & 1) ? w2 : w1;
    float val = w[(((size_t)(lvl * 512 + co) * 512) + ci) * 2 + k];
    WpT[e] = f2bf(val);
}

// GEMM: out[n][co] = act( A-window . W + bias ), all activations bf16.
// 256n x 128co tile, BK=64 ci-block, dual-tap shared-A (264-row LDS window),
// B fragments direct from global (k-major WpT), 128 MFMA per barrier-pair.
// HAS_RES: v = relu(relu(acc+b) + res_bf16); in-place-safe (lane-owned elems).
template <bool HAS_RES>
__global__ __launch_bounds__(256, 2) void conv_gemm(
    const unsigned short* __restrict__ Ain, const unsigned short* __restrict__ WpT,
    const float* __restrict__ bias, const unsigned short* __restrict__ resB,
    unsigned short* __restrict__ OutB, int d)
{
    __shared__ unsigned short sA[264 * 64];   // rows rbase-8 .. rbase+255, 64 halves (ci block)

    const int tid = threadIdx.x;
    const int wave = tid >> 6, lane = tid & 63;
    const int co0 = blockIdx.x * 128;
    const int n0 = blockIdx.y * 256;
    const int rbase = (n0 >> 10) * LROWS + LPAD + (n0 & (LL - 1));
    const int r8 = lane >> 3;                  // row within 8-row segment
    const int cswz = (lane & 7) ^ r8;          // swizzled 16B chunk (global side)
    const int wm = wave * 64;                  // wave n-stripe
    const int lm = lane & 15, quad = lane >> 4;

    f32x4 acc[4][8];
#pragma unroll
    for (int i = 0; i < 4; ++i)
#pragma unroll
        for (int j = 0; j < 8; ++j) acc[i][j] = (f32x4){0.f, 0.f, 0.f, 0.f};

    for (int it = 0; it < 8; ++it) {
        const int ci0 = it * 64;

        // stage A: 33 segments x (8 rows x 64 halves = 1KB); wave0 takes 9
        const unsigned short* gA = Ain + (size_t)(rbase - 8 + r8) * CC + ci0 + cswz * 8;
        for (int s = wave; s < 33; s += 4)
            llds16(gA + (size_t)s * 8 * CC, sA + s * 8 * 64);
        __syncthreads();

#pragma unroll
        for (int t = 0; t < 2; ++t) {
            const int shift = t ? d : 0;               // t=0: kidx 0..511; t=1: kidx 512.. (past)
            const int rowoff = 8 - shift + wm;
            const int key = (lm + 8 - shift) & 7;      // LDS chunk XOR key per tap
#pragma unroll
            for (int kc = 0; kc < 2; ++kc) {
                const int jb = t * 64 + it * 8 + kc * 4 + quad;   // global 16B k-chunk
                bf16x8 af[4], bfr[8];
#pragma unroll
                for (int mt = 0; mt < 4; ++mt) {
                    int row = rowoff + mt * 16 + lm;
                    af[mt] = *(const bf16x8*)&sA[row * 64 + (((kc * 4 + quad) ^ key) * 8)];
                }
                const unsigned short* bbase = WpT + ((size_t)jb * 512 + co0 + lm) * 8;
#pragma unroll
                for (int nt = 0; nt < 8; ++nt)
                    bfr[nt] = *(const bf16x8*)(bbase + (size_t)nt * 16 * 8);
#pragma unroll
                for (int mt = 0; mt < 4; ++mt)
#pragma unroll
                    for (int nt = 0; nt < 8; ++nt)
                        acc[mt][nt] = __builtin_amdgcn_mfma_f32_16x16x32_bf16(
                            af[mt], bfr[nt], acc[mt][nt], 0, 0, 0);
            }
        }
        __syncthreads();
    }

    // epilogue: C/D layout col(co)=lane&15, row(n)=quad*4+reg
    float bv[8];
#pragma unroll
    for (int nt = 0; nt < 8; ++nt) bv[nt] = bias[co0 + nt * 16 + lm];

#pragma unroll
    for (int mt = 0; mt < 4; ++mt) {
        int prow0 = rbase + wm + mt * 16 + quad * 4;
#pragma unroll
        for (int nt = 0; nt < 8; ++nt) {
            int co = co0 + nt * 16 + lm;
#pragma unroll
            for (int r = 0; r < 4; ++r) {
                size_t off = (size_t)(prow0 + r) * CC + co;
                float v = acc[mt][nt][r] + bv[nt];
                v = fmaxf(v, 0.f);
                if (HAS_RES) {
                    v += bf2f(resB[off]);
                    v = fmaxf(v, 0.f);
                }
                OutB[off] = f2bf(v);
            }
        }
    }
}

// y[n][o] = mask[n] * (sum_c h[n][c]*dw[o][c] + db[o]);  one wave per n (bf16 h)
__global__ __launch_bounds__(256) void decode_kernel(
    const unsigned short* __restrict__ H, const float* __restrict__ dw,
    const float* __restrict__ db, const int* __restrict__ mask,
    float* __restrict__ out)
{
    __shared__ float sw[OUTD * CC];
    for (int i = threadIdx.x; i < OUTD * CC; i += 256) sw[i] = dw[i];
    __syncthreads();

    int wave = threadIdx.x >> 6, lane = threadIdx.x & 63;
    int n = blockIdx.x * 4 + wave;
    int prow = (n >> 10) * LROWS + LPAD + (n & (LL - 1));

    float hv[8];
#pragma unroll
    for (int j = 0; j < 8; ++j) hv[j] = bf2f(H[(size_t)prow * CC + lane + j * 64]);

    float accv[OUTD];
#pragma unroll
    for (int o = 0; o < OUTD; ++o) {
        float s = 0.f;
#pragma unroll
        for (int j = 0; j < 8; ++j) s += hv[j] * sw[o * CC + lane + j * 64];
        accv[o] = s;
    }
    float myv = 0.f;
#pragma unroll
    for (int o = 0; o < OUTD; ++o) {
        float s = accv[o];
#pragma unroll
        for (int m = 32; m; m >>= 1) s += __shfl_xor(s, m, 64);
        if (lane == o) myv = s;
    }
    if (lane < OUTD) {
        float mk = (mask[n] != 0) ? 1.f : 0.f;
        out[(size_t)n * OUTD + lane] = (myv + db[lane]) * mk;
    }
}

extern "C" void kernel_launch(void* const* d_in, const int* in_sizes, int n_in,
                              void* d_out, int out_size, void* d_ws, size_t ws_size,
                              hipStream_t stream)
{
    const int* x = (const int*)d_in[0];
    const int* mask = (const int*)d_in[1];   // jnp bool_ staged as int32
    const float* emb = (const float*)d_in[2];
    const float* w1 = (const float*)d_in[3];
    const float* b1 = (const float*)d_in[4];
    const float* w2 = (const float*)d_in[5];
    const float* b2 = (const float*)d_in[6];
    const float* dw = (const float*)d_in[7];
    const float* db = (const float*)d_in[8];
    float* out = (float*)d_out;

    char* ws = (char*)d_ws;
    const size_t HBB = (size_t)BB * LROWS * CC * 2;       // 33.8 MB (padded bf16)
    unsigned short* Hb0 = (unsigned short*)ws;
    unsigned short* Hb1 = (unsigned short*)(ws + HBB);
    unsigned short* WpT = (unsigned short*)(ws + 2 * HBB); // k-major bf16 weights, 8 MB

    zero_pad_kernel<<<128, 256, 0, stream>>>(Hb0, Hb1);
    embed_kernel<<<(NN * 64) / 256, 256, 0, stream>>>(x, emb, Hb0);
    pack_w_kernel<<<(NLEVS * 2 * CC * 1024) / 256, 256, 0, stream>>>(w1, w2, WpT);

    dim3 g(CC / 128, NN / 256);   // 4 co-blocks x 128 n-blocks = 512 = 2/CU
    for (int i = 0; i < NLEVS; ++i) {
        int d = 1 << i;
        const unsigned short* W1 = WpT + (size_t)(i * 2 + 0) * CC * 1024;
        const unsigned short* W2 = WpT + (size_t)(i * 2 + 1) * CC * 1024;
        // conv1: A=Hb0 -> Hb1
        conv_gemm<false><<<g, 256, 0, stream>>>(Hb0, W1, b1 + i * CC, nullptr, Hb1, d);
        // conv2: A=Hb1, res=Hb0 (bf16), out=Hb0 (in place, lane-owned)
        conv_gemm<true><<<g, 256, 0, stream>>>(Hb1, W2, b2 + i * CC, Hb0, Hb0, d);
    }
    decode_kernel<<<NN / 4, 256, 0, stream>>>(Hb0, dw, db, mask, out);
}

// Round 5
// 439.196 us; speedup vs baseline: 1.6847x; 1.0911x over previous
//
#include <hip/hip_runtime.h>
#include <stdint.h>

#define BB 32
#define LL 1024
#define CC 512
#define NN (BB * LL)      // 32768 positions
#define NLEVS 4
#define OUTD 11
#define LPAD 8            // zero pad rows per sequence (>= max dilation)
#define LROWS (LL + LPAD) // 1032 padded rows per sequence

typedef __attribute__((ext_vector_type(8))) short bf16x8;
typedef __attribute__((ext_vector_type(4))) float f32x4;

static __device__ __forceinline__ unsigned short f2bf(float f) {
    union { float f; uint32_t u; } v; v.f = f;
    uint32_t u = v.u;
    uint32_t r = (u + 0x7fffu + ((u >> 16) & 1u)) >> 16;  // RNE
    return (unsigned short)r;
}
static __device__ __forceinline__ float bf2f(unsigned short h) {
    union { uint32_t u; float f; } v; v.u = ((uint32_t)h) << 16;
    return v.f;
}

// async 16B global -> LDS (wave-uniform LDS base + lane*16)
static __device__ __forceinline__ void llds16(const unsigned short* g, unsigned short* l) {
    __builtin_amdgcn_global_load_lds(
        (const __attribute__((address_space(1))) unsigned int*)g,
        (__attribute__((address_space(3))) unsigned int*)l, 16, 0, 0);
}

// zero the LPAD pad rows of both bf16 activation buffers
__global__ __launch_bounds__(256) void zero_pad_kernel(
    unsigned short* __restrict__ Hb0, unsigned short* __restrict__ Hb1)
{
    int t = blockIdx.x * 256 + threadIdx.x;        // 32768 uint4 stores
    unsigned short* base = (t >> 14) ? Hb1 : Hb0;
    int rem = t & 16383;
    int p = rem >> 9;                               // sequence 0..31
    int q = rem & 511;                              // 512 uint4 per pad region
    size_t off = (size_t)p * (LROWS * CC) + (size_t)q * 8;
    *(uint4*)(base + off) = (uint4){0u, 0u, 0u, 0u};
}

// h0 bf16 padded: Hb0[prow][c] = bf16(emb[x[n]][c])
__global__ __launch_bounds__(256) void embed_kernel(
    const int* __restrict__ x, const float* __restrict__ emb,
    unsigned short* __restrict__ Hb0)
{
    int t = blockIdx.x * 256 + threadIdx.x;   // 8 halves each (64 chunks/row)
    int n = t >> 6;
    int c8 = (t & 63) * 8;
    int idx = x[n];
    const float* src = emb + (size_t)idx * CC + c8;
    float4 v0 = *(const float4*)src;
    float4 v1 = *(const float4*)(src + 4);
    ushort4 a, b;
    a.x = f2bf(v0.x); a.y = f2bf(v0.y); a.z = f2bf(v0.z); a.w = f2bf(v0.w);
    b.x = f2bf(v1.x); b.y = f2bf(v1.y); b.z = f2bf(v1.z); b.w = f2bf(v1.w);
    int prow = (n >> 10) * LROWS + LPAD + (n & (LL - 1));
    unsigned short* dst = Hb0 + (size_t)prow * CC + c8;
    *(ushort4*)dst = a;
    *(ushort4*)(dst + 4) = b;
}

// WpT[cv][j][co][h]: k-chunk-major packed weights for direct B-fragment loads.
// kidx = j*8+h; kidx<512 -> tap "current" (k=1, ci=kidx); kidx>=512 -> k=0, ci=kidx-512.
__global__ __launch_bounds__(256) void pack_w_kernel(
    const float* __restrict__ w1, const float* __restrict__ w2, unsigned short* __restrict__ WpT)
{
    int e = blockIdx.x * 256 + threadIdx.x;    // 8 * 524288 elements
    int cv = e >> 19;                           // conv 0..7 (lvl*2+conv)
    int r = e & 524287;
    int j = r >> 12;                            // 0..127
    int co = (r >> 3) & 511;
    int h = r & 7;
    int kidx = j * 8 + h;
    int k = (kidx < 512) ? 1 : 0;
    int ci = kidx & 511;
    int lvl = cv >> 1;
    const float* w = (cv & 1) ? w2 : w1;
    float val = w[(((size_t)(lvl * 512 + co) * 512) + ci) * 2 + k];
    WpT[e] = f2bf(val);
}

// GEMM: out[n][co] = act( A-window . W + bias ), all activations bf16.
// 128n x 128co tile, BK=64 ci-block, dual-tap shared-A (136-row LDS window),
// B fragments direct from global (k-major WpT).
// 1D grid 1024 with XCD swizzle: the 4 co-blocks sharing an A-window map to
// the same XCD (bid&7) so its private L2 fetches A once.
// HAS_RES: v = relu(relu(acc+b) + res_bf16); in-place-safe (lane-owned elems).
template <bool HAS_RES>
__global__ __launch_bounds__(256, 4) void conv_gemm(
    const unsigned short* __restrict__ Ain, const unsigned short* __restrict__ WpT,
    const float* __restrict__ bias, const unsigned short* __restrict__ resB,
    unsigned short* __restrict__ OutB, int d)
{
    __shared__ unsigned short sA[136 * 64];   // rows rbase-8 .. rbase+127

    const int tid = threadIdx.x;
    const int wave = tid >> 6, lane = tid & 63;

    const int bid = blockIdx.x;               // 0..1023
    const int xcd = bid & 7;
    const int local = bid >> 3;               // 0..127
    const int cb = local >> 5;                // 0..3
    const int nb = xcd + 8 * (local & 31);    // 0..255
    const int co0 = cb * 128;
    const int n0 = nb * 128;

    const int rbase = (n0 >> 10) * LROWS + LPAD + (n0 & (LL - 1));
    const int r8 = lane >> 3;                  // row within 8-row segment
    const int cswz = (lane & 7) ^ r8;          // swizzled 16B chunk (global side)
    const int wm = (wave >> 1) * 64;           // wave n-stripe
    const int wn = (wave & 1) * 64;            // wave co-stripe
    const int lm = lane & 15, quad = lane >> 4;

    f32x4 acc[4][4];
#pragma unroll
    for (int i = 0; i < 4; ++i)
#pragma unroll
        for (int j = 0; j < 4; ++j) acc[i][j] = (f32x4){0.f, 0.f, 0.f, 0.f};

    for (int it = 0; it < 8; ++it) {
        const int ci0 = it * 64;

        // stage A: 17 segments x (8 rows x 64 halves = 1KB)
        const unsigned short* gA = Ain + (size_t)(rbase - 8 + r8) * CC + ci0 + cswz * 8;
#pragma unroll
        for (int s4 = 0; s4 < 4; ++s4) {
            int s = s4 * 4 + wave;
            llds16(gA + (size_t)s * 8 * CC, sA + s * 8 * 64);
        }
        if (wave == 0) llds16(gA + (size_t)16 * 8 * CC, sA + 16 * 8 * 64);
        __syncthreads();

#pragma unroll
        for (int t = 0; t < 2; ++t) {
            const int shift = t ? d : 0;               // t=0: kidx 0..511; t=1: past tap
            const int rowoff = 8 - shift + wm;
            const int key = (lm + 8 - shift) & 7;      // LDS chunk XOR key per tap
#pragma unroll
            for (int kc = 0; kc < 2; ++kc) {
                const int jb = t * 64 + it * 8 + kc * 4 + quad;   // global 16B k-chunk
                bf16x8 af[4], bfr[4];
#pragma unroll
                for (int mt = 0; mt < 4; ++mt) {
                    int row = rowoff + mt * 16 + lm;
                    af[mt] = *(const bf16x8*)&sA[row * 64 + (((kc * 4 + quad) ^ key) * 8)];
                }
                const unsigned short* bbase = WpT + ((size_t)jb * 512 + co0 + wn + lm) * 8;
#pragma unroll
                for (int nt = 0; nt < 4; ++nt)
                    bfr[nt] = *(const bf16x8*)(bbase + (size_t)nt * 16 * 8);
#pragma unroll
                for (int mt = 0; mt < 4; ++mt)
#pragma unroll
                    for (int nt = 0; nt < 4; ++nt)
                        acc[mt][nt] = __builtin_amdgcn_mfma_f32_16x16x32_bf16(
                            af[mt], bfr[nt], acc[mt][nt], 0, 0, 0);
            }
        }
        __syncthreads();
    }

    // epilogue: C/D layout col(co)=lane&15, row(n)=quad*4+reg
    float bv[4];
#pragma unroll
    for (int nt = 0; nt < 4; ++nt) bv[nt] = bias[co0 + wn + nt * 16 + lm];

#pragma unroll
    for (int mt = 0; mt < 4; ++mt) {
        int prow0 = rbase + wm + mt * 16 + quad * 4;
#pragma unroll
        for (int nt = 0; nt < 4; ++nt) {
            int co = co0 + wn + nt * 16 + lm;
#pragma unroll
            for (int r = 0; r < 4; ++r) {
                size_t off = (size_t)(prow0 + r) * CC + co;
                float v = acc[mt][nt][r] + bv[nt];
                v = fmaxf(v, 0.f);
                if (HAS_RES) {
                    v += bf2f(resB[off]);
                    v = fmaxf(v, 0.f);
                }
                OutB[off] = f2bf(v);
            }
        }
    }
}

// y[n][o] = mask[n] * (sum_c h[n][c]*dw[o][c] + db[o]);  one wave per n (bf16 h)
__global__ __launch_bounds__(256) void decode_kernel(
    const unsigned short* __restrict__ H, const float* __restrict__ dw,
    const float* __restrict__ db, const int* __restrict__ mask,
    float* __restrict__ out)
{
    __shared__ float sw[OUTD * CC];
    for (int i = threadIdx.x; i < OUTD * CC; i += 256) sw[i] = dw[i];
    __syncthreads();

    int wave = threadIdx.x >> 6, lane = threadIdx.x & 63;
    int n = blockIdx.x * 4 + wave;
    int prow = (n >> 10) * LROWS + LPAD + (n & (LL - 1));

    float hv[8];
#pragma unroll
    for (int j = 0; j < 8; ++j) hv[j] = bf2f(H[(size_t)prow * CC + lane + j * 64]);

    float accv[OUTD];
#pragma unroll
    for (int o = 0; o < OUTD; ++o) {
        float s = 0.f;
#pragma unroll
        for (int j = 0; j < 8; ++j) s += hv[j] * sw[o * CC + lane + j * 64];
        accv[o] = s;
    }
    float myv = 0.f;
#pragma unroll
    for (int o = 0; o < OUTD; ++o) {
        float s = accv[o];
#pragma unroll
        for (int m = 32; m; m >>= 1) s += __shfl_xor(s, m, 64);
        if (lane == o) myv = s;
    }
    if (lane < OUTD) {
        float mk = (mask[n] != 0) ? 1.f : 0.f;
        out[(size_t)n * OUTD + lane] = (myv + db[lane]) * mk;
    }
}

extern "C" void kernel_launch(void* const* d_in, const int* in_sizes, int n_in,
                              void* d_out, int out_size, void* d_ws, size_t ws_size,
                              hipStream_t stream)
{
    const int* x = (const int*)d_in[0];
    const int* mask = (const int*)d_in[1];   // jnp bool_ staged as int32
    const float* emb = (const float*)d_in[2];
    const float* w1 = (const float*)d_in[3];
    const float* b1 = (const float*)d_in[4];
    const float* w2 = (const float*)d_in[5];
    const float* b2 = (const float*)d_in[6];
    const float* dw = (const float*)d_in[7];
    const float* db = (const float*)d_in[8];
    float* out = (float*)d_out;

    char* ws = (char*)d_ws;
    const size_t HBB = (size_t)BB * LROWS * CC * 2;       // 33.8 MB (padded bf16)
    unsigned short* Hb0 = (unsigned short*)ws;
    unsigned short* Hb1 = (unsigned short*)(ws + HBB);
    unsigned short* WpT = (unsigned short*)(ws + 2 * HBB); // k-major bf16 weights, 8 MB

    zero_pad_kernel<<<128, 256, 0, stream>>>(Hb0, Hb1);
    embed_kernel<<<(NN * 64) / 256, 256, 0, stream>>>(x, emb, Hb0);
    pack_w_kernel<<<(NLEVS * 2 * CC * 1024) / 256, 256, 0, stream>>>(w1, w2, WpT);

    const int grid = (CC / 128) * (NN / 128);   // 4 * 256 = 1024 blocks = 4/CU
    for (int i = 0; i < NLEVS; ++i) {
        int d = 1 << i;
        const unsigned short* W1 = WpT + (size_t)(i * 2 + 0) * CC * 1024;
        const unsigned short* W2 = WpT + (size_t)(i * 2 + 1) * CC * 1024;
        // conv1: A=Hb0 -> Hb1
        conv_gemm<false><<<grid, 256, 0, stream>>>(Hb0, W1, b1 + i * CC, nullptr, Hb1, d);
        // conv2: A=Hb1, res=Hb0 (bf16), out=Hb0 (in place, lane-owned)
        conv_gemm<true><<<grid, 256, 0, stream>>>(Hb1, W2, b2 + i * CC, Hb0, Hb0, d);
    }
    decode_kernel<<<NN / 4, 256, 0, stream>>>(Hb0, dw, db, mask, out);
}